// Round 3
// baseline (1717.692 us; speedup 1.0000x reference)
//
#include <hip/hip_runtime.h>

#define NW 4096
#define SEQ 33
#define CC 256
#define NTOK 131072
#define NKC 27

typedef unsigned short u16;
typedef __attribute__((ext_vector_type(8))) short s16x8;
typedef __attribute__((ext_vector_type(4))) short s16x4;
typedef __attribute__((ext_vector_type(4))) float f32x4;

#define MFMA16(a,b,c) __builtin_amdgcn_mfma_f32_16x16x32_bf16((a),(b),(c),0,0,0)

__device__ __forceinline__ float bu2f(u16 u){ return __uint_as_float(((unsigned int)u)<<16); }
__device__ __forceinline__ u16 f2bu(float f){
  unsigned int u = __float_as_uint(f);
  return (u16)((u + 0x7FFFu + ((u>>16)&1u)) >> 16);
}

// ---- f32 -> bf16 convert (float4 vectorized) ----
__global__ void k_cvt(const float* __restrict__ in, u16* __restrict__ out, int n4){
  int stride = gridDim.x * blockDim.x;
  for (int i = blockIdx.x*blockDim.x + threadIdx.x; i < n4; i += stride){
    float4 v = ((const float4*)in)[i];
    s16x4 o;
    o[0] = (short)f2bu(v.x); o[1] = (short)f2bu(v.y);
    o[2] = (short)f2bu(v.z); o[3] = (short)f2bu(v.w);
    ((s16x4*)out)[i] = o;
  }
}

// ---- transpose f32 (R x C) -> bf16 (C x R) ----
__global__ void k_tr(const float* __restrict__ in, u16* __restrict__ out, int R, int C){
  int stride = gridDim.x * blockDim.x;
  int total = R*C;
  for (int i = blockIdx.x*blockDim.x + threadIdx.x; i < total; i += stride){
    int r = i / C, c = i - r*C;
    out[c*R + r] = f2bu(in[i]);
  }
}

// ---- relay rows (s=0) into x buffer ----
__global__ void k_relay(const float* __restrict__ rt, u16* __restrict__ xg){
  int stride = gridDim.x * blockDim.x;
  for (int i = blockIdx.x*blockDim.x + threadIdx.x; i < NW*CC; i += stride){
    int w = i >> 8, c = i & 255;
    xg[(w*SEQ)*CC + c] = f2bu(rt[i]);
  }
}

// ---- CPE gather + BN + residual -> x rows s=1..32 ----
__global__ void k_cpe(const float* __restrict__ data, const u16* __restrict__ datab,
                      const int* __restrict__ neigh, const float* __restrict__ cpw,
                      const float* __restrict__ bng, const float* __restrict__ bnb,
                      const float* __restrict__ bnm, const float* __restrict__ bnv,
                      u16* __restrict__ xg){
  int n = blockIdx.x*4 + (threadIdx.x >> 6);
  int lane = threadIdx.x & 63;
  int c0 = lane*4;
  float a0=0.f, a1=0.f, a2=0.f, a3=0.f;
  const int* nr = neigh + n*NKC;
  for (int k = 0; k < NKC; ++k){
    int idx = nr[k];
    s16x4 d = *(const s16x4*)(datab + idx*CC + c0);
    float4 wv = *(const float4*)(cpw + k*CC + c0);
    a0 += bu2f((u16)d[0])*wv.x;
    a1 += bu2f((u16)d[1])*wv.y;
    a2 += bu2f((u16)d[2])*wv.z;
    a3 += bu2f((u16)d[3])*wv.w;
  }
  float4 dv = *(const float4*)(data + n*CC + c0);
  float4 g  = *(const float4*)(bng + c0);
  float4 b  = *(const float4*)(bnb + c0);
  float4 m  = *(const float4*)(bnm + c0);
  float4 vv = *(const float4*)(bnv + c0);
  float x0 = dv.x + (a0 - m.x)*rsqrtf(vv.x + 1e-5f)*g.x + b.x;
  float x1 = dv.y + (a1 - m.y)*rsqrtf(vv.y + 1e-5f)*g.y + b.y;
  float x2 = dv.z + (a2 - m.z)*rsqrtf(vv.z + 1e-5f)*g.z + b.z;
  float x3 = dv.w + (a3 - m.w)*rsqrtf(vv.w + 1e-5f)*g.w + b.w;
  int w = n >> 5, s = (n & 31) + 1;
  s16x4 o;
  o[0]=(short)f2bu(x0); o[1]=(short)f2bu(x1); o[2]=(short)f2bu(x2); o[3]=(short)f2bu(x3);
  *(s16x4*)(xg + (w*SEQ + s)*CC + c0) = o;
}

// ---- fused per-window transformer block ----
struct SharedT {
  u16 xs[33][264];            // residual stream (bf16), ld pad 8
  u16 hs[48][264];            // layernorm output (rows 33..47 stay zero)
  u16 qs[48][40];
  u16 ks[48][40];
  u16 vT[32][72];             // v transposed [d][t]; t>=48 stays zero
  u16 Ps[48][72];             // softmax probs; rows 33..47 stay zero
  u16 och[48][40];            // per-head attention out
  union { float ss[48][52]; u16 mch[48][136]; } u2;  // scores / ffn-mid chunk
};
static_assert(sizeof(SharedT) <= 80*1024, "LDS budget for 2 blocks/CU");

__global__ __launch_bounds__(256,2) void k_window(
    const u16* __restrict__ xg,
    const u16* __restrict__ qkvT, const u16* __restrict__ projT,
    const u16* __restrict__ fc1T, const u16* __restrict__ fc2T,
    const float* __restrict__ n1g, const float* __restrict__ n1b,
    const float* __restrict__ qkvb, const float* __restrict__ projb,
    const float* __restrict__ n2g, const float* __restrict__ n2b,
    const float* __restrict__ fc1b, const float* __restrict__ fc2b,
    float* __restrict__ out)
{
  __shared__ __align__(16) SharedT L;
  const int tid = threadIdx.x;
  const int lane = tid & 63;
  const int wid = tid >> 6;
  const int l15 = lane & 15;
  const int lg8 = (lane >> 4) * 8;
  const int lg4 = (lane >> 4) * 4;
  const int w = blockIdx.x;
  const f32x4 fzero = {0.f,0.f,0.f,0.f};

  // zero all LDS (hs rows>=33, vT cols>=48, Ps rows>=33 must be 0)
  {
    f32x4* p = (f32x4*)&L;
    const int n16 = (int)(sizeof(SharedT)/16);
    for (int i = tid; i < n16; i += 256) p[i] = fzero;
  }
  __syncthreads();

  // load x window (33 rows x 256 bf16)
  for (int ci = tid; ci < SEQ*32; ci += 256){
    int r = ci >> 5, cp = (ci & 31) << 3;
    *(s16x8*)&L.xs[r][cp] = *(const s16x8*)(xg + (w*SEQ + r)*CC + cp);
  }
  __syncthreads();

  auto LN = [&](const float* gg, const float* bb){
    for (int r = wid; r < SEQ; r += 4){
      int c0 = lane*4;
      s16x4 xv = *(const s16x4*)&L.xs[r][c0];
      float v0 = bu2f((u16)xv[0]), v1 = bu2f((u16)xv[1]);
      float v2 = bu2f((u16)xv[2]), v3 = bu2f((u16)xv[3]);
      float s  = v0+v1+v2+v3;
      float s2 = v0*v0+v1*v1+v2*v2+v3*v3;
      #pragma unroll
      for (int msk = 1; msk < 64; msk <<= 1){
        s  += __shfl_xor(s, msk);
        s2 += __shfl_xor(s2, msk);
      }
      float mu = s * (1.f/256.f);
      float var = s2 * (1.f/256.f) - mu*mu;
      float rs = rsqrtf(var + 1e-5f);
      float4 gv = *(const float4*)(gg + c0);
      float4 bv = *(const float4*)(bb + c0);
      s16x4 o;
      o[0] = (short)f2bu((v0-mu)*rs*gv.x + bv.x);
      o[1] = (short)f2bu((v1-mu)*rs*gv.y + bv.y);
      o[2] = (short)f2bu((v2-mu)*rs*gv.z + bv.z);
      o[3] = (short)f2bu((v3-mu)*rs*gv.w + bv.w);
      *(s16x4*)&L.hs[r][c0] = o;
    }
  };
  LN(n1g, n1b);
  __syncthreads();

  // proj accumulators: accP[ni][m] covers output tile (rows m*16.., cols (wid+4*ni)*16..)
  f32x4 accP[4][3];
  #pragma unroll
  for (int ni = 0; ni < 4; ++ni)
    #pragma unroll
    for (int m = 0; m < 3; ++m) accP[ni][m] = fzero;

  for (int h = 0; h < 8; ++h){
    // (a) q,k,v slice for this head — balanced n-major job split with B-reg cache.
    // wave w covers n-major tile-jobs: w0:{n0 m0-2, n1 m0-1} w1:{n1 m2, n2 m0-2}
    //                                  w2:{n3 m0-2, n4 m0-1} w3:{n4 m2, n5 m0-2}
    {
      int nbase = wid + (wid >> 1);
      #pragma unroll
      for (int p = 0; p < 2; ++p){
        int n = nbase + p;
        int m_lo = (p == 0) ? ((wid & 1) ? 2 : 0) : 0;
        int m_hi = (p == 0) ? 2 : ((wid & 1) ? 2 : 1);
        int sel = n >> 1, sub = n & 1;
        int ncol = sel*256 + h*32 + sub*16 + l15;
        const u16* wrow = qkvT + ncol*CC + lg8;
        s16x8 bf[8];
        #pragma unroll
        for (int kk = 0; kk < 8; ++kk) bf[kk] = *(const s16x8*)(wrow + kk*32);
        float bias = qkvb[ncol];
        int colh = sub*16 + l15;
        for (int m = m_lo; m <= m_hi; ++m){
          f32x4 acc = fzero;
          #pragma unroll
          for (int kk = 0; kk < 8; ++kk){
            s16x8 a = *(const s16x8*)&L.hs[m*16 + l15][kk*32 + lg8];
            acc = MFMA16(a, bf[kk], acc);
          }
          int rb = m*16 + lg4;
          #pragma unroll
          for (int jj = 0; jj < 4; ++jj){
            float val = acc[jj] + bias;
            int row = rb + jj;
            if (sel == 0)      L.qs[row][colh] = f2bu(val);
            else if (sel == 1) L.ks[row][colh] = f2bu(val);
            else               L.vT[colh][row] = f2bu(val);
          }
        }
      }
    }
    __syncthreads();
    // (b) scores = (q*scale) @ k^T   (K=32, one MFMA per tile)
    for (int j = wid; j < 9; j += 4){
      int m = j / 3, n = j - (j/3)*3;
      s16x8 a   = *(const s16x8*)&L.qs[m*16 + l15][lg8];
      s16x8 bfr = *(const s16x8*)&L.ks[n*16 + l15][lg8];
      f32x4 acc = fzero;
      acc = MFMA16(a, bfr, acc);
      int col = n*16 + l15;
      int rb = m*16 + lg4;
      #pragma unroll
      for (int jj = 0; jj < 4; ++jj)
        L.u2.ss[rb + jj][col] = acc[jj] * 0.17677669529663687f;
    }
    __syncthreads();
    // (c) row softmax -> P (cols>=33 written as 0)
    for (int r = wid; r < SEQ; r += 4){
      float v = (lane < SEQ) ? L.u2.ss[r][lane] : -1e30f;
      float mx = v;
      #pragma unroll
      for (int msk = 1; msk < 64; msk <<= 1) mx = fmaxf(mx, __shfl_xor(mx, msk));
      float p = (lane < SEQ) ? __expf(v - mx) : 0.f;
      float sm = p;
      #pragma unroll
      for (int msk = 1; msk < 64; msk <<= 1) sm += __shfl_xor(sm, msk);
      L.Ps[r][lane] = f2bu(p / sm);
    }
    __syncthreads();
    // (d) out_head = P @ V  (K=64 incl zero padding)
    for (int j = wid; j < 6; j += 4){
      int m = j >> 1, n = j & 1;
      f32x4 acc = fzero;
      #pragma unroll
      for (int kk = 0; kk < 2; ++kk){
        s16x8 a   = *(const s16x8*)&L.Ps[m*16 + l15][kk*32 + lg8];
        s16x8 bfr = *(const s16x8*)&L.vT[n*16 + l15][kk*32 + lg8];
        acc = MFMA16(a, bfr, acc);
      }
      int col = n*16 + l15;
      int rb = m*16 + lg4;
      #pragma unroll
      for (int jj = 0; jj < 4; ++jj)
        L.och[rb + jj][col] = f2bu(acc[jj]);
    }
    __syncthreads();
    // (e) proj partial accumulate — n-major, B fragment loaded once per (h,n).
    // NOTE: no trailing barrier. (e) reads only och/projT/registers; next write
    // to och is (d) of head h+1, separated by the (a)/(b)/(c) barriers; (a) of
    // head h+1 writes qs/ks/vT only — disjoint. Safe overlap.
    #pragma unroll
    for (int ni = 0; ni < 4; ++ni){
      int n = wid + 4*ni;
      s16x8 bfr = *(const s16x8*)(projT + (n*16 + l15)*CC + h*32 + lg8);
      #pragma unroll
      for (int m = 0; m < 3; ++m){
        s16x8 a = *(const s16x8*)&L.och[m*16 + l15][lg8];
        accP[ni][m] = MFMA16(a, bfr, accP[ni][m]);
      }
    }
  }

  // proj bias + residual into xs (each (row,col) owned by exactly one thread)
  #pragma unroll
  for (int ni = 0; ni < 4; ++ni){
    int col = (wid + 4*ni)*16 + l15;
    float pb = projb[col];
    #pragma unroll
    for (int m = 0; m < 3; ++m){
      #pragma unroll
      for (int jj = 0; jj < 4; ++jj){
        int row = m*16 + lg4 + jj;
        if (row < SEQ){
          float x = bu2f(L.xs[row][col]) + accP[ni][m][jj] + pb;
          L.xs[row][col] = f2bu(x);
        }
      }
    }
  }
  __syncthreads();

  LN(n2g, n2b);
  __syncthreads();

  f32x4 accF[4][3];
  #pragma unroll
  for (int ni = 0; ni < 4; ++ni)
    #pragma unroll
    for (int m = 0; m < 3; ++m) accF[ni][m] = fzero;

  for (int nc = 0; nc < 8; ++nc){
    // fc1 chunk (128 cols) + gelu -> mch — n-major, B cached in regs
    for (int n = wid; n < 8; n += 4){
      int ncol = nc*128 + n*16 + l15;
      const u16* wrow = fc1T + ncol*CC + lg8;
      s16x8 bf[8];
      #pragma unroll
      for (int kk = 0; kk < 8; ++kk) bf[kk] = *(const s16x8*)(wrow + kk*32);
      float bias = fc1b[ncol];
      int colc = n*16 + l15;
      #pragma unroll
      for (int m = 0; m < 3; ++m){
        f32x4 acc = fzero;
        #pragma unroll
        for (int kk = 0; kk < 8; ++kk){
          s16x8 a = *(const s16x8*)&L.hs[m*16 + l15][kk*32 + lg8];
          acc = MFMA16(a, bf[kk], acc);
        }
        int rb = m*16 + lg4;
        #pragma unroll
        for (int jj = 0; jj < 4; ++jj){
          float xv = acc[jj] + bias;
          // gelu(tanh approx) == x * sigmoid(2z), z = 0.79788456*(x + 0.044715 x^3)
          float z2 = 1.5957691216057308f*(xv + 0.044715f*xv*xv*xv);
          float gl = xv / (1.f + __expf(-z2));
          L.u2.mch[rb + jj][colc] = f2bu(gl);
        }
      }
    }
    __syncthreads();
    // fc2 partial accumulate (K-chunk = 128) — n-major, B cached in regs
    #pragma unroll
    for (int ni = 0; ni < 4; ++ni){
      int n = wid + 4*ni;
      const u16* wrow = fc2T + (n*16 + l15)*1024 + nc*128 + lg8;
      s16x8 bf[4];
      #pragma unroll
      for (int kk = 0; kk < 4; ++kk) bf[kk] = *(const s16x8*)(wrow + kk*32);
      #pragma unroll
      for (int m = 0; m < 3; ++m){
        #pragma unroll
        for (int kk = 0; kk < 4; ++kk){
          s16x8 a = *(const s16x8*)&L.u2.mch[m*16 + l15][kk*32 + lg8];
          accF[ni][m] = MFMA16(a, bf[kk], accF[ni][m]);
        }
      }
    }
    __syncthreads();
  }

  // final: x + ffn, write data_out / rt
  #pragma unroll
  for (int ni = 0; ni < 4; ++ni){
    int col = (wid + 4*ni)*16 + l15;
    float fb = fc2b[col];
    #pragma unroll
    for (int m = 0; m < 3; ++m){
      #pragma unroll
      for (int jj = 0; jj < 4; ++jj){
        int row = m*16 + lg4 + jj;
        if (row < SEQ){
          float x = bu2f(L.xs[row][col]) + accF[ni][m][jj] + fb;
          if (row == 0) out[NTOK*CC + w*CC + col] = x;          // relay tokens
          else          out[(w*32 + row - 1)*CC + col] = x;      // data_out
        }
      }
    }
  }
}

extern "C" void kernel_launch(void* const* d_in, const int* in_sizes, int n_in,
                              void* d_out, int out_size, void* d_ws, size_t ws_size,
                              hipStream_t stream){
  const float* data  = (const float*)d_in[0];
  const float* relay = (const float*)d_in[1];
  const int*   neigh = (const int*)d_in[2];
  const float* cpw   = (const float*)d_in[3];
  const float* bng   = (const float*)d_in[4];
  const float* bnb   = (const float*)d_in[5];
  const float* bnm   = (const float*)d_in[6];
  const float* bnv   = (const float*)d_in[7];
  const float* n1g   = (const float*)d_in[8];
  const float* n1b   = (const float*)d_in[9];
  const float* qkvw  = (const float*)d_in[10];
  const float* qkvb  = (const float*)d_in[11];
  const float* projw = (const float*)d_in[12];
  const float* projb = (const float*)d_in[13];
  const float* n2g   = (const float*)d_in[14];
  const float* n2b   = (const float*)d_in[15];
  const float* fc1w  = (const float*)d_in[16];
  const float* fc1b  = (const float*)d_in[17];
  const float* fc2w  = (const float*)d_in[18];
  const float* fc2b  = (const float*)d_in[19];

  char* ws = (char*)d_ws;
  u16* datab = (u16*)ws;                 // 131072*256*2      = 67,108,864 B
  u16* xg    = (u16*)(ws + 67108864);    // 135168*256*2      = 69,206,016 B
  u16* qkvT  = (u16*)(ws + 136314880);   // 768*256*2         =    393,216 B
  u16* projT = (u16*)(ws + 136708096);   // 256*256*2         =    131,072 B
  u16* fc1T  = (u16*)(ws + 136839168);   // 1024*256*2        =    524,288 B
  u16* fc2T  = (u16*)(ws + 137363456);   // 256*1024*2        =    524,288 B

  k_cvt<<<4096, 256, 0, stream>>>(data, datab, NTOK*CC/4);
  k_tr<<<256, 256, 0, stream>>>(qkvw, qkvT, 256, 768);
  k_tr<<<256, 256, 0, stream>>>(projw, projT, 256, 256);
  k_tr<<<256, 256, 0, stream>>>(fc1w, fc1T, 256, 1024);
  k_tr<<<256, 256, 0, stream>>>(fc2w, fc2T, 1024, 256);
  k_relay<<<1024, 256, 0, stream>>>(relay, xg);
  k_cpe<<<NTOK/4, 256, 0, stream>>>(data, datab, neigh, cpw, bng, bnb, bnm, bnv, xg);
  k_window<<<NW, 256, 0, stream>>>(xg, qkvT, projT, fc1T, fc2T,
                                   n1g, n1b, qkvb, projb, n2g, n2b, fc1b, fc2b,
                                   (float*)d_out);
}

// Round 4
// 1540.989 us; speedup vs baseline: 1.1147x; 1.1147x over previous
//
#include <hip/hip_runtime.h>

#define NW 4096
#define SEQ 33
#define CC 256
#define NTOK 131072
#define NKC 27

typedef unsigned short u16;
typedef __attribute__((ext_vector_type(8))) short s16x8;
typedef __attribute__((ext_vector_type(4))) short s16x4;
typedef __attribute__((ext_vector_type(4))) float f32x4;

#define MFMA16(a,b,c) __builtin_amdgcn_mfma_f32_16x16x32_bf16((a),(b),(c),0,0,0)

__device__ __forceinline__ float bu2f(u16 u){ return __uint_as_float(((unsigned int)u)<<16); }
__device__ __forceinline__ u16 f2bu(float f){
  unsigned int u = __float_as_uint(f);
  return (u16)((u + 0x7FFFu + ((u>>16)&1u)) >> 16);
}

// ---- f32 -> bf16 convert (float4 vectorized) ----
__global__ void k_cvt(const float* __restrict__ in, u16* __restrict__ out, int n4){
  int stride = gridDim.x * blockDim.x;
  for (int i = blockIdx.x*blockDim.x + threadIdx.x; i < n4; i += stride){
    float4 v = ((const float4*)in)[i];
    s16x4 o;
    o[0] = (short)f2bu(v.x); o[1] = (short)f2bu(v.y);
    o[2] = (short)f2bu(v.z); o[3] = (short)f2bu(v.w);
    ((s16x4*)out)[i] = o;
  }
}

// ---- transpose f32 (R x C) -> bf16 (C x R) ----
__global__ void k_tr(const float* __restrict__ in, u16* __restrict__ out, int R, int C){
  int stride = gridDim.x * blockDim.x;
  int total = R*C;
  for (int i = blockIdx.x*blockDim.x + threadIdx.x; i < total; i += stride){
    int r = i / C, c = i - r*C;
    out[c*R + r] = f2bu(in[i]);
  }
}

// ---- relay rows (s=0) into x buffer ----
__global__ void k_relay(const float* __restrict__ rt, u16* __restrict__ xg){
  int stride = gridDim.x * blockDim.x;
  for (int i = blockIdx.x*blockDim.x + threadIdx.x; i < NW*CC; i += stride){
    int w = i >> 8, c = i & 255;
    xg[(w*SEQ)*CC + c] = f2bu(rt[i]);
  }
}

// ---- CPE gather + BN + residual -> x rows s=1..32 ----
__global__ void k_cpe(const float* __restrict__ data, const u16* __restrict__ datab,
                      const int* __restrict__ neigh, const float* __restrict__ cpw,
                      const float* __restrict__ bng, const float* __restrict__ bnb,
                      const float* __restrict__ bnm, const float* __restrict__ bnv,
                      u16* __restrict__ xg){
  int n = blockIdx.x*4 + (threadIdx.x >> 6);
  int lane = threadIdx.x & 63;
  int c0 = lane*4;
  float a0=0.f, a1=0.f, a2=0.f, a3=0.f;
  const int* nr = neigh + n*NKC;
  for (int k = 0; k < NKC; ++k){
    int idx = nr[k];
    s16x4 d = *(const s16x4*)(datab + idx*CC + c0);
    float4 wv = *(const float4*)(cpw + k*CC + c0);
    a0 += bu2f((u16)d[0])*wv.x;
    a1 += bu2f((u16)d[1])*wv.y;
    a2 += bu2f((u16)d[2])*wv.z;
    a3 += bu2f((u16)d[3])*wv.w;
  }
  float4 dv = *(const float4*)(data + n*CC + c0);
  float4 g  = *(const float4*)(bng + c0);
  float4 b  = *(const float4*)(bnb + c0);
  float4 m  = *(const float4*)(bnm + c0);
  float4 vv = *(const float4*)(bnv + c0);
  float x0 = dv.x + (a0 - m.x)*rsqrtf(vv.x + 1e-5f)*g.x + b.x;
  float x1 = dv.y + (a1 - m.y)*rsqrtf(vv.y + 1e-5f)*g.y + b.y;
  float x2 = dv.z + (a2 - m.z)*rsqrtf(vv.z + 1e-5f)*g.z + b.z;
  float x3 = dv.w + (a3 - m.w)*rsqrtf(vv.w + 1e-5f)*g.w + b.w;
  int w = n >> 5, s = (n & 31) + 1;
  s16x4 o;
  o[0]=(short)f2bu(x0); o[1]=(short)f2bu(x1); o[2]=(short)f2bu(x2); o[3]=(short)f2bu(x3);
  *(s16x4*)(xg + (w*SEQ + s)*CC + c0) = o;
}

// ---- fused per-window transformer block, fat-phase / all-heads layout ----
// Aliasing discipline (all padded garbage is FINITE by construction):
//  A: hs (LN out; rows 33-47 zero from init) ∪ P[8][33][72] (per-head probs;
//     cols 33-47 get explicit zeros from masked exp, cols 48-63 re-zeroed per
//     wave after the qkv barrier, cols 64-71 never read)
//  B: Q (dead after scores barrier) ∪ och (written by PV)
//  C2: K (dead after scores barrier) ∪ mch (FFN mid chunk)
//  VT[256][72]: cols(t) 0-47 written by qkv; 48-63 stay zero from init.
struct SharedW {
  u16 xs[33][264];                                   // 17,424 B residual
  union { u16 hs[48][264]; u16 P[8][33][72]; } A;    // 38,016 B
  union { u16 Q[48][264];  u16 och[48][264]; } B;    // 25,344 B
  union { u16 K[48][264];  u16 mch[48][264]; } C2;   // 25,344 B
  u16 VT[256][72];                                   // 36,864 B
};                                                   // 142,992 B total
static_assert(sizeof(SharedW) <= 160*1024, "LDS budget (1 block/CU)");

__global__ __launch_bounds__(512,2) void k_window(
    const u16* __restrict__ xg,
    const u16* __restrict__ qkvT, const u16* __restrict__ projT,
    const u16* __restrict__ fc1T, const u16* __restrict__ fc2T,
    const float* __restrict__ n1g, const float* __restrict__ n1b,
    const float* __restrict__ qkvb, const float* __restrict__ projb,
    const float* __restrict__ n2g, const float* __restrict__ n2b,
    const float* __restrict__ fc1b, const float* __restrict__ fc2b,
    float* __restrict__ out)
{
  __shared__ __align__(16) SharedW L;
  const int tid  = threadIdx.x;
  const int lane = tid & 63;
  const int wid  = tid >> 6;          // 0..7
  const int l15  = lane & 15;
  const int lg8  = (lane >> 4) * 8;
  const int lg4  = (lane >> 4) * 4;
  const int w    = blockIdx.x;
  const f32x4 fzero = {0.f,0.f,0.f,0.f};

  // zero everything except xs (xs fully overwritten by the load below)
  {
    f32x4* p = (f32x4*)((char*)&L + sizeof(L.xs));
    const int n16 = (int)((sizeof(SharedW) - sizeof(L.xs))/16);
    for (int i = tid; i < n16; i += 512) p[i] = fzero;
  }
  // load x window (33 rows x 256 bf16)
  for (int ci = tid; ci < SEQ*32; ci += 512){
    int r = ci >> 5, cp = (ci & 31) << 3;
    *(s16x8*)&L.xs[r][cp] = *(const s16x8*)(xg + (w*SEQ + r)*CC + cp);
  }
  __syncthreads();

  auto LN = [&](const float* gg, const float* bb){
    for (int r = wid; r < SEQ; r += 8){
      int c0 = lane*4;
      s16x4 xv = *(const s16x4*)&L.xs[r][c0];
      float v0 = bu2f((u16)xv[0]), v1 = bu2f((u16)xv[1]);
      float v2 = bu2f((u16)xv[2]), v3 = bu2f((u16)xv[3]);
      float s  = v0+v1+v2+v3;
      float s2 = v0*v0+v1*v1+v2*v2+v3*v3;
      #pragma unroll
      for (int msk = 1; msk < 64; msk <<= 1){
        s  += __shfl_xor(s, msk);
        s2 += __shfl_xor(s2, msk);
      }
      float mu = s * (1.f/256.f);
      float var = s2 * (1.f/256.f) - mu*mu;
      float rs = rsqrtf(var + 1e-5f);
      float4 gv = *(const float4*)(gg + c0);
      float4 bv = *(const float4*)(bb + c0);
      s16x4 o;
      o[0] = (short)f2bu((v0-mu)*rs*gv.x + bv.x);
      o[1] = (short)f2bu((v1-mu)*rs*gv.y + bv.y);
      o[2] = (short)f2bu((v2-mu)*rs*gv.z + bv.z);
      o[3] = (short)f2bu((v3-mu)*rs*gv.w + bv.w);
      *(s16x4*)&L.A.hs[r][c0] = o;
    }
  };
  LN(n1g, n1b);
  __syncthreads();

  // ===== QKV: 48x256 @ 256x768, all heads in one phase =====
  {
    s16x8 ahs[3][8];
    #pragma unroll
    for (int m = 0; m < 3; ++m)
      #pragma unroll
      for (int kk = 0; kk < 8; ++kk)
        ahs[m][kk] = *(const s16x8*)&L.A.hs[m*16 + l15][kk*32 + lg8];
    for (int i = 0; i < 6; ++i){
      int n = wid*6 + i;                 // n-tile 0..47
      int sel = n >> 4;                  // 0=q 1=k 2=v
      int cn  = (n & 15)*16 + l15;       // col within q/k/v
      int ncol = n*16 + l15;             // col within 768
      const u16* wrow = qkvT + ncol*CC + lg8;
      s16x8 bf[8];
      #pragma unroll
      for (int kk = 0; kk < 8; ++kk) bf[kk] = *(const s16x8*)(wrow + kk*32);
      float bias = qkvb[ncol];
      f32x4 acc[3] = {fzero, fzero, fzero};
      #pragma unroll
      for (int kk = 0; kk < 8; ++kk)
        #pragma unroll
        for (int m = 0; m < 3; ++m)
          acc[m] = MFMA16(ahs[m][kk], bf[kk], acc[m]);
      #pragma unroll
      for (int m = 0; m < 3; ++m)
        #pragma unroll
        for (int jj = 0; jj < 4; ++jj){
          int row = m*16 + lg4 + jj;
          float val = acc[m][jj] + bias;
          if (sel == 0)      L.B.Q[row][cn]  = f2bu(val*0.17677669529663687f); // fold attn scale
          else if (sel == 1) L.C2.K[row][cn] = f2bu(val);
          else               L.VT[cn][row]   = f2bu(val);
        }
    }
  }
  __syncthreads();

  // ===== attention scores + softmax, fully per-wave (wave = head) =====
  {
    const int h = wid;
    // re-zero P[h] cols 48..63 (may be hs/LN1 leftovers due to aliasing)
    {
      s16x8 z = {0,0,0,0,0,0,0,0};
      for (int i = lane; i < 66; i += 64){
        int r = i >> 1, c = 48 + (i & 1)*8;
        *(s16x8*)&L.A.P[h][r][c] = z;
      }
    }
    s16x8 aq[3], bk[3];
    #pragma unroll
    for (int m = 0; m < 3; ++m) aq[m] = *(const s16x8*)&L.B.Q[m*16 + l15][h*32 + lg8];
    #pragma unroll
    for (int n = 0; n < 3; ++n) bk[n] = *(const s16x8*)&L.C2.K[n*16 + l15][h*32 + lg8];
    f32x4 sc[3][3];
    #pragma unroll
    for (int m = 0; m < 3; ++m)
      #pragma unroll
      for (int n = 0; n < 3; ++n)
        sc[m][n] = MFMA16(aq[m], bk[n], fzero);
    // in-register row softmax: row = m*16 + (lane>>4)*4 + jj, cols 16n + l15
    #pragma unroll
    for (int m = 0; m < 3; ++m)
      #pragma unroll
      for (int jj = 0; jj < 4; ++jj){
        float a0 = sc[m][0][jj];
        float a1 = sc[m][1][jj];
        float a2 = (l15 == 0) ? sc[m][2][jj] : -1e30f;   // only col 32 valid in tile n=2
        float mx = fmaxf(fmaxf(a0, a1), a2);
        #pragma unroll
        for (int msk = 1; msk < 16; msk <<= 1) mx = fmaxf(mx, __shfl_xor(mx, msk));
        float e0 = __expf(a0 - mx), e1 = __expf(a1 - mx), e2 = __expf(a2 - mx);
        float sm = e0 + e1 + e2;
        #pragma unroll
        for (int msk = 1; msk < 16; msk <<= 1) sm += __shfl_xor(sm, msk);
        float inv = 1.f / sm;
        int row = m*16 + lg4 + jj;
        if (row < SEQ){
          L.A.P[h][row][l15]      = f2bu(e0*inv);
          L.A.P[h][row][16 + l15] = f2bu(e1*inv);
          L.A.P[h][row][32 + l15] = f2bu(e2*inv);   // l15>0 writes exact zeros (cols 33-47)
        }
      }
  }
  __syncthreads();   // Q dead; och (alias of Q) may now be written

  // ===== PV per-wave, write och =====
  {
    const int h = wid;
    s16x8 pa[3][2];
    #pragma unroll
    for (int m = 0; m < 3; ++m){
      int row = m*16 + l15; if (row > 32) row = 32;   // clamped: garbage rows are finite dups
      pa[m][0] = *(const s16x8*)&L.A.P[h][row][lg8];
      pa[m][1] = *(const s16x8*)&L.A.P[h][row][32 + lg8];
    }
    f32x4 acc[2][3];
    #pragma unroll
    for (int n = 0; n < 2; ++n){
      s16x8 bv0 = *(const s16x8*)&L.VT[h*32 + n*16 + l15][lg8];
      s16x8 bv1 = *(const s16x8*)&L.VT[h*32 + n*16 + l15][32 + lg8];
      #pragma unroll
      for (int m = 0; m < 3; ++m){
        f32x4 a = MFMA16(pa[m][0], bv0, fzero);
        acc[n][m] = MFMA16(pa[m][1], bv1, a);
      }
    }
    #pragma unroll
    for (int n = 0; n < 2; ++n)
      #pragma unroll
      for (int m = 0; m < 3; ++m)
        #pragma unroll
        for (int jj = 0; jj < 4; ++jj)
          L.B.och[m*16 + lg4 + jj][h*32 + n*16 + l15] = f2bu(acc[n][m][jj]);
  }
  __syncthreads();

  // ===== proj (K=256 full) + residual into xs =====
  {
    s16x8 ao[3][8];
    #pragma unroll
    for (int m = 0; m < 3; ++m)
      #pragma unroll
      for (int kk = 0; kk < 8; ++kk)
        ao[m][kk] = *(const s16x8*)&L.B.och[m*16 + l15][kk*32 + lg8];
    #pragma unroll
    for (int i = 0; i < 2; ++i){
      int ncol = (wid*2 + i)*16 + l15;
      const u16* wrow = projT + ncol*CC + lg8;
      s16x8 bf[8];
      #pragma unroll
      for (int kk = 0; kk < 8; ++kk) bf[kk] = *(const s16x8*)(wrow + kk*32);
      f32x4 acc[3] = {fzero, fzero, fzero};
      #pragma unroll
      for (int kk = 0; kk < 8; ++kk)
        #pragma unroll
        for (int m = 0; m < 3; ++m)
          acc[m] = MFMA16(ao[m][kk], bf[kk], acc[m]);
      float pb = projb[ncol];
      #pragma unroll
      for (int m = 0; m < 3; ++m)
        #pragma unroll
        for (int jj = 0; jj < 4; ++jj){
          int row = m*16 + lg4 + jj;
          if (row < SEQ){
            float x = bu2f(L.xs[row][ncol]) + acc[m][jj] + pb;
            L.xs[row][ncol] = f2bu(x);
          }
        }
    }
  }
  __syncthreads();

  LN(n2g, n2b);
  __syncthreads();

  // ===== FFN: 4 chunks of 256 mid-cols; fc2 accumulated in registers =====
  f32x4 accF[2][3];
  #pragma unroll
  for (int i = 0; i < 2; ++i)
    #pragma unroll
    for (int m = 0; m < 3; ++m) accF[i][m] = fzero;

  {
    s16x8 ah2[3][8];
    #pragma unroll
    for (int m = 0; m < 3; ++m)
      #pragma unroll
      for (int kk = 0; kk < 8; ++kk)
        ah2[m][kk] = *(const s16x8*)&L.A.hs[m*16 + l15][kk*32 + lg8];

    for (int nc = 0; nc < 4; ++nc){
      // fc1 chunk + gelu -> mch
      #pragma unroll
      for (int i = 0; i < 2; ++i){
        int nl = (wid*2 + i)*16 + l15;        // 0..255 within chunk
        int ncol = nc*256 + nl;
        const u16* wrow = fc1T + ncol*CC + lg8;
        s16x8 bf[8];
        #pragma unroll
        for (int kk = 0; kk < 8; ++kk) bf[kk] = *(const s16x8*)(wrow + kk*32);
        float bias = fc1b[ncol];
        f32x4 acc[3] = {fzero, fzero, fzero};
        #pragma unroll
        for (int kk = 0; kk < 8; ++kk)
          #pragma unroll
          for (int m = 0; m < 3; ++m)
            acc[m] = MFMA16(ah2[m][kk], bf[kk], acc[m]);
        #pragma unroll
        for (int m = 0; m < 3; ++m)
          #pragma unroll
          for (int jj = 0; jj < 4; ++jj){
            int row = m*16 + lg4 + jj;
            float xv = acc[m][jj] + bias;
            // gelu(tanh) == x * sigmoid(2z), z = 0.79788456*(x + 0.044715 x^3)
            float z2 = 1.5957691216057308f*(xv + 0.044715f*xv*xv*xv);
            float gl = xv / (1.f + __expf(-z2));
            L.C2.mch[row][nl] = f2bu(gl);
          }
      }
      __syncthreads();
      // fc2 partial accumulate (K-chunk = 256), A read once for both i
      {
        const u16* wr0 = fc2T + ((wid*2 + 0)*16 + l15)*1024 + nc*256 + lg8;
        const u16* wr1 = fc2T + ((wid*2 + 1)*16 + l15)*1024 + nc*256 + lg8;
        s16x8 b0[8], b1[8];
        #pragma unroll
        for (int kk = 0; kk < 8; ++kk){ b0[kk] = *(const s16x8*)(wr0 + kk*32);
                                        b1[kk] = *(const s16x8*)(wr1 + kk*32); }
        #pragma unroll
        for (int kk = 0; kk < 8; ++kk)
          #pragma unroll
          for (int m = 0; m < 3; ++m){
            s16x8 a = *(const s16x8*)&L.C2.mch[m*16 + l15][kk*32 + lg8];
            accF[0][m] = MFMA16(a, b0[kk], accF[0][m]);
            accF[1][m] = MFMA16(a, b1[kk], accF[1][m]);
          }
      }
      __syncthreads();
    }
  }

  // ===== final: x + ffn, write data_out / rt =====
  #pragma unroll
  for (int i = 0; i < 2; ++i){
    int col = (wid*2 + i)*16 + l15;
    float fb = fc2b[col];
    #pragma unroll
    for (int m = 0; m < 3; ++m)
      #pragma unroll
      for (int jj = 0; jj < 4; ++jj){
        int row = m*16 + lg4 + jj;
        if (row < SEQ){
          float x = bu2f(L.xs[row][col]) + accF[i][m][jj] + fb;
          if (row == 0) out[NTOK*CC + w*CC + col] = x;          // relay tokens
          else          out[(w*32 + row - 1)*CC + col] = x;      // data_out
        }
      }
  }
}

extern "C" void kernel_launch(void* const* d_in, const int* in_sizes, int n_in,
                              void* d_out, int out_size, void* d_ws, size_t ws_size,
                              hipStream_t stream){
  const float* data  = (const float*)d_in[0];
  const float* relay = (const float*)d_in[1];
  const int*   neigh = (const int*)d_in[2];
  const float* cpw   = (const float*)d_in[3];
  const float* bng   = (const float*)d_in[4];
  const float* bnb   = (const float*)d_in[5];
  const float* bnm   = (const float*)d_in[6];
  const float* bnv   = (const float*)d_in[7];
  const float* n1g   = (const float*)d_in[8];
  const float* n1b   = (const float*)d_in[9];
  const float* qkvw  = (const float*)d_in[10];
  const float* qkvb  = (const float*)d_in[11];
  const float* projw = (const float*)d_in[12];
  const float* projb = (const float*)d_in[13];
  const float* n2g   = (const float*)d_in[14];
  const float* n2b   = (const float*)d_in[15];
  const float* fc1w  = (const float*)d_in[16];
  const float* fc1b  = (const float*)d_in[17];
  const float* fc2w  = (const float*)d_in[18];
  const float* fc2b  = (const float*)d_in[19];

  char* ws = (char*)d_ws;
  u16* datab = (u16*)ws;                 // 131072*256*2      = 67,108,864 B
  u16* xg    = (u16*)(ws + 67108864);    // 135168*256*2      = 69,206,016 B
  u16* qkvT  = (u16*)(ws + 136314880);   // 768*256*2         =    393,216 B
  u16* projT = (u16*)(ws + 136708096);   // 256*256*2         =    131,072 B
  u16* fc1T  = (u16*)(ws + 136839168);   // 1024*256*2        =    524,288 B
  u16* fc2T  = (u16*)(ws + 137363456);   // 256*1024*2        =    524,288 B

  k_cvt<<<4096, 256, 0, stream>>>(data, datab, NTOK*CC/4);
  k_tr<<<256, 256, 0, stream>>>(qkvw, qkvT, 256, 768);
  k_tr<<<256, 256, 0, stream>>>(projw, projT, 256, 256);
  k_tr<<<256, 256, 0, stream>>>(fc1w, fc1T, 256, 1024);
  k_tr<<<256, 256, 0, stream>>>(fc2w, fc2T, 1024, 256);
  k_relay<<<1024, 256, 0, stream>>>(relay, xg);
  k_cpe<<<NTOK/4, 256, 0, stream>>>(data, datab, neigh, cpw, bng, bnb, bnm, bnv, xg);
  k_window<<<NW, 512, 0, stream>>>(xg, qkvT, projT, fc1T, fc2T,
                                   n1g, n1b, qkvb, projb, n2g, n2b, fc1b, fc2b,
                                   (float*)d_out);
}